// Round 21
// baseline (196.117 us; speedup 1.0000x reference)
//
#include <hip/hip_runtime.h>
#include <hip/hip_cooperative_groups.h>

namespace cg = cooperative_groups;

#define L_SIG 3000
#define CIN 64
#define COUT 128
#define KW 25
#define TOUT 2976
#define FMAXB 973

// ws byte layout (r16-proven):
#define AE_BYTE   0
#define AO_BYTE   1572864
#define BC_BYTE   3145728
#define BS_BYTE   6291456
#define TC_BYTE   9437184
#define TS_BYTE   12582912
#define WC_BYTE   15728640
#define SP_BYTE   22544384
#define AR_BYTE   31457280
#define AI_BYTE   31981568

typedef _Float16 f16x8 __attribute__((ext_vector_type(8)));
typedef float f32x4 __attribute__((ext_vector_type(4)));

typedef __attribute__((address_space(1))) const unsigned GU;
typedef __attribute__((address_space(3))) unsigned LU;
#define GL16(g, l) __builtin_amdgcn_global_load_lds((GU*)(g), (LU*)(l), 16, 0, 0)

#define TWO_PI_OVER_L 0.00209439510239319549f

__device__ __forceinline__ float2 h2f2(unsigned u) {
    union { unsigned u; _Float16 h[2]; } p; p.u = u;
    return make_float2((float)p.h[0], (float)p.h[1]);
}
__device__ __forceinline__ unsigned f2h2(float a, float b) {
    union { unsigned u; _Float16 h[2]; } p;
    p.h[0] = (_Float16)a; p.h[1] = (_Float16)b; return p.u;
}

// ================= phase bodies (r16-passing math, verbatim) ============

// prep unit u in [0,4776): fold|Bcos/Bsin|gen_T|w_dft|zero
__device__ __forceinline__ void dev_prep(int u, int tid, const float* __restrict__ sig,
                                         const float* __restrict__ w,
                                         char* __restrict__ wsb, float* wL) {
    const int startv[5] = {0,122,244,366,488};
    const int binsv[5]  = {123,123,123,123,485};

    if (u < 512) {                           // ---- fold: xe / xo (swizzled)
        const float* x = sig + (size_t)u * L_SIG;
        _Float16* AE = (_Float16*)(wsb + AE_BYTE);
        _Float16* AO = (_Float16*)(wsb + AO_BYTE);
        for (int g2 = tid; g2 < 384; g2 += 256) {
            int half = (g2 >= 192);
            int g = g2 - (half ? 192 : 0);
            union { _Float16 h[8]; uint4 u4; } p;
            p.u4 = make_uint4(0, 0, 0, 0);
            if (g < 188) {
                int k0 = g * 8;
                float4 f0 = *(const float4*)(x + k0);
                float4 f1 = *(const float4*)(x + k0 + 4);
                float4 m0 = *(const float4*)(x + 2992 - k0);
                float4 m1 = *(const float4*)(x + 2996 - k0);
                float mir0 = k0 ? x[3000 - k0] : 0.f;
                float fwd[8]  = {f0.x,f0.y,f0.z,f0.w,f1.x,f1.y,f1.z,f1.w};
                float span[8] = {m0.x,m0.y,m0.z,m0.w,m1.x,m1.y,m1.z,m1.w};
                #pragma unroll
                for (int j = 0; j < 8; ++j) {
                    int k = k0 + j;
                    float mv = (j == 0) ? mir0 : span[8 - j];   // x[3000-k]
                    float xe, xo;
                    if (k == 0)         { xe = fwd[0];      xo = 0.f; }
                    else if (k < 1500)  { xe = fwd[j] + mv; xo = fwd[j] - mv; }
                    else if (k == 1500) { xe = fwd[j];      xo = 0.f; }
                    else                { xe = 0.f;         xo = 0.f; }
                    p.h[j] = (_Float16)(half ? xo : xe);
                }
            }
            int gsw = (g & ~7) | ((g & 7) ^ (u & 7));
            ((uint4*)(half ? AO : AE))[(size_t)u * 192 + gsw] = p.u4;
        }

    } else if (u < 2560) {                   // ---- Bcos / Bsin (swizzled)
        int q = u - 512;
        int isin = (q >= 1024);
        int f = q & 1023;
        _Float16* Bm = (_Float16*)(wsb + (isin ? BS_BYTE : BC_BYTE));
        int g = tid;
        if (g >= 192) return;
        union { _Float16 h[8]; uint4 u4; } p;
        p.u4 = make_uint4(0, 0, 0, 0);
        if (f < FMAXB) {
            int k0 = g * 8;
            int m0 = (int)(((long long)f * k0) % 3000);
            float s0, c0, sw, cw;
            __sincosf((float)m0 * TWO_PI_OVER_L, &s0, &c0);
            __sincosf((float)f * TWO_PI_OVER_L, &sw, &cw);
            float rr = c0, ri = -s0;         // (cos, -sin) at k0
            #pragma unroll
            for (int j = 0; j < 8; ++j) {
                p.h[j] = (_Float16)(isin ? ri : rr);
                float nr = rr * cw + ri * sw;
                float ni = ri * cw - rr * sw;
                rr = nr; ri = ni;
            }
        }
        int gsw = (g & ~7) | ((g & 7) ^ (f & 7));
        ((uint4*)Bm)[(size_t)f * 192 + gsw] = p.u4;

    } else if (u < 4096) {                   // ---- Tcos / Tsin (per-band, linear)
        const int tb4[5] = {0, 24576, 49152, 73728, 98304};
        int t = u - 2560;                    // 0..1535
        int m = tid >> 7;                    // 0 = cos, 1 = sin
        int gi = tid & 127;
        int band, g;
        if (gi < 64) { band = gi >> 4; g = gi & 15; }
        else         { band = 4;       g = gi - 64; }
        int Kb8 = (band < 4) ? 16 : 64;      // granules per row
        int bins = binsv[band];
        int fl0 = g * 8;
        int f0 = startv[band] + fl0;
        union { _Float16 h[8]; uint4 u4; } p;
        p.u4 = make_uint4(0, 0, 0, 0);
        int m0 = (f0 * t) % 3000;
        float s0, c0, sw, cw;
        __sincosf((float)m0 * TWO_PI_OVER_L, &s0, &c0);
        __sincosf((float)t * TWO_PI_OVER_L, &sw, &cw);
        float rr = c0, ri = -s0;             // (cos, -sin) at f0
        #pragma unroll
        for (int j = 0; j < 8; ++j) {
            if (fl0 + j < bins) p.h[j] = (_Float16)(m ? ri : rr);
            float nr = rr * cw + ri * sw;    // advance f by 1
            float ni = ri * cw - rr * sw;
            rr = nr; ri = ni;
        }
        uint4* Tm = (uint4*)(wsb + (m ? TS_BYTE : TC_BYTE));
        Tm[(size_t)tb4[band] + (size_t)t * Kb8 + g] = p.u4;

    } else if (u < 4520) {                   // ---- weight DFT, 4x-parallel over i
        _Float16* Wc = (_Float16*)(wsb + WC_BYTE);
        const int n_ov[5]   = {25,25,25,25,28};
        const size_t wbase[5] = {0, 393600, 787200, 1180800, 1574400};  // halfs
        int q = u - 4096;
        int o, fchunk;
        if (q < 200) { o = q >> 1; fchunk = q & 1; }          // bands 0-3
        else { int q2 = q - 200; o = 100 + (q2 >> 3); fchunk = q2 & 7; }  // band 4
        int band = min(o / 25, 4);
        int o_local = o - band * 25;
        int bins = binsv[band];
        const float* wrow = w + (size_t)o * CIN * KW;
        for (int k = tid; k < CIN * KW; k += 256) wL[k] = wrow[k];
        __syncthreads();
        int fl = tid & 63, iq = tid >> 6;    // f-lane, i-quarter
        int f = fchunk * 64 + fl;
        if (f >= bins) return;
        int n_o = n_ov[band];
        int fg = startv[band] + f;
        float ws_, wc_;
        __sincosf((float)fg * TWO_PI_OVER_L, &ws_, &wc_);
        float wr = wc_, wi = ws_;            // conj roots: +sin
        unsigned* outp = (unsigned*)Wc + (wbase[band] >> 1) + ((size_t)f * n_o + o_local) * 64;
        #pragma unroll 4
        for (int i = iq * 16; i < iq * 16 + 16; ++i) {
            float ar = 0.f, ai = 0.f;
            float rr = 1.0f, ri = 0.0f;
            const float* wv = wL + i * KW;
            #pragma unroll
            for (int t = 0; t < KW; ++t) {
                float x = wv[t];
                ar = fmaf(x, rr, ar);
                ai = fmaf(x, ri, ai);
                float nr = fmaf(-ri, wi, rr * wr);
                float ni = fmaf( ri, wr, rr * wi);
                rr = nr; ri = ni;
            }
            outp[i] = f2h2(ar, ai);
        }

    } else {                                 // ---- zero Ar+Ai (contiguous 1 MB)
        uint4* Az = (uint4*)(wsb + AR_BYTE);
        int q = u - 4520;
        Az[(size_t)q * 256 + tid] = make_uint4(0, 0, 0, 0);   // 65536 uint4
    }
}

// fwd GEMM unit u in [0,256): z=u&1, Mtile=(u>>1)&7, ftile=u>>4. BK=128.
__device__ __forceinline__ void dev_dft(int u, int tid, const char* __restrict__ wsb,
                                        float* __restrict__ Sp,
                                        _Float16* AsB, _Float16* BsB) {
    int z = u & 1;
    const _Float16* A = (const _Float16*)(wsb + (z ? AO_BYTE : AE_BYTE));
    const _Float16* B = (const _Float16*)(wsb + (z ? BS_BYTE : BC_BYTE));
    int row0 = ((u >> 1) & 7) * 64;
    int col0 = (u >> 4) * 64;
    const int nkt = 12;
    int wid = tid >> 6, lane = tid & 63;
    int wr = wid >> 1, wc = wid & 1;
    f32x4 acc[2][2] = {};

    auto stage = [&](int kt, int buf) {      // 8 GL16 per thread
        int k0g = kt * 16;
        #pragma unroll
        for (int it = 0; it < 4; ++it) {
            int cb = it * 256 + wid * 64;
            int c = cb + lane;
            int ar = c >> 4, cir = c & 15;
            GL16((const char*)A + ((size_t)(row0 + ar) * 192 + k0g + cir) * 16,
                 (char*)AsB + buf * 16384 + cb * 16);
            GL16((const char*)B + ((size_t)(col0 + ar) * 192 + k0g + cir) * 16,
                 (char*)BsB + buf * 16384 + cb * 16);
        }
    };
    stage(0, 0);
    for (int kt = 0; kt < nkt; ++kt) {
        int cur = kt & 1;
        asm volatile("s_waitcnt vmcnt(0)" ::: "memory");
        __syncthreads();
        if (kt + 1 < nkt) stage(kt + 1, cur ^ 1);
        #pragma unroll
        for (int ks = 0; ks < 4; ++ks) {
            f16x8 av[2], bv[2];
            #pragma unroll
            for (int m = 0; m < 2; ++m) {
                int r = wr * 32 + m * 16 + (lane & 15);
                int gq = ks * 4 + (lane >> 4);
                int g = (gq & ~7) | ((gq & 7) ^ (r & 7));
                av[m] = *(const f16x8*)(AsB + cur * 8192 + r * 128 + g * 8);
            }
            #pragma unroll
            for (int n = 0; n < 2; ++n) {
                int r = wc * 32 + n * 16 + (lane & 15);
                int gq = ks * 4 + (lane >> 4);
                int g = (gq & ~7) | ((gq & 7) ^ (r & 7));
                bv[n] = *(const f16x8*)(BsB + cur * 8192 + r * 128 + g * 8);
            }
            #pragma unroll
            for (int m = 0; m < 2; ++m)
                #pragma unroll
                for (int n = 0; n < 2; ++n)
                    acc[m][n] = __builtin_amdgcn_mfma_f32_16x16x32_f16(
                        av[m], bv[n], acc[m][n], 0, 0, 0);
        }
    }
    #pragma unroll
    for (int m = 0; m < 2; ++m)
        #pragma unroll
        for (int n = 0; n < 2; ++n) {
            int colf = col0 + wc * 32 + n * 16 + (lane & 15);
            int scol = 2 * colf + z;
            int rowb = row0 + wr * 32 + m * 16 + (lane >> 4) * 4;
            *(float4*)(Sp + (size_t)scol * 512 + rowb) = *(float4*)&acc[m][n];
        }
}

// mix unit u in [0,977)
__device__ __forceinline__ void dev_mix(int u, int tid, const float* __restrict__ Sp,
                                        const _Float16* __restrict__ Wc,
                                        char* __restrict__ wsb,
                                        float* s_re, float* s_im) {
    const int startv[5] = {0,122,244,366,488};
    const int n_ov[5]   = {25,25,25,25,28};
    const int kbv[5]    = {128,128,128,128,512};
    const size_t wbase[5] = {0, 393600, 787200, 1180800, 1574400};  // halfs
    const size_t arbase[5] = {0, 32768, 65536, 98304, 131072};      // halfs
    const int cumb[6] = {0, 123, 246, 369, 492, 977};
    int band = 0;
    while (u >= cumb[band + 1]) band++;
    int f_local = u - cumb[band];
    int fg = startv[band] + f_local;

    const float* p0 = Sp + (size_t)(2 * fg) * 512;      // re col (im at +512)
    #pragma unroll
    for (int e = 0; e < 2; ++e) {
        int row = tid + e * 256;                         // b*64+i
        int b = row >> 6, i = row & 63;
        s_re[b * 72 + i] = p0[row];
        s_im[b * 72 + i] = p0[512 + row];
    }
    __syncthreads();

    int o_local = tid >> 3, b = tid & 7;
    int n_o = n_ov[band];
    if (o_local >= n_o) return;
    const uint4* wp4 = (const uint4*)((const unsigned*)Wc + (wbase[band] >> 1) +
                                      ((size_t)f_local * n_o + o_local) * 64);
    const float* lre = s_re + b * 72;
    const float* lim = s_im + b * 72;
    float xr = 0.f, xi = 0.f;
    #pragma unroll
    for (int ii = 0; ii < 16; ++ii) {
        float4 r4 = *(const float4*)(lre + ii * 4);
        float4 i4 = *(const float4*)(lim + ii * 4);
        uint4 wq = wp4[ii];
        float2 wv;
        wv = h2f2(wq.x);
        xr = fmaf(r4.x, wv.x, xr); xr = fmaf(-i4.x, wv.y, xr);
        xi = fmaf(r4.x, wv.y, xi); xi = fmaf( i4.x, wv.x, xi);
        wv = h2f2(wq.y);
        xr = fmaf(r4.y, wv.x, xr); xr = fmaf(-i4.y, wv.y, xr);
        xi = fmaf(r4.y, wv.y, xi); xi = fmaf( i4.y, wv.x, xi);
        wv = h2f2(wq.z);
        xr = fmaf(r4.z, wv.x, xr); xr = fmaf(-i4.z, wv.y, xr);
        xi = fmaf(r4.z, wv.y, xi); xi = fmaf( i4.z, wv.x, xi);
        wv = h2f2(wq.w);
        xr = fmaf(r4.w, wv.x, xr); xr = fmaf(-i4.w, wv.y, xr);
        xi = fmaf(r4.w, wv.y, xi); xi = fmaf( i4.w, wv.x, xi);
    }
    float scale = (fg == 0 ? 1.0f : 2.0f) / 3000.0f;
    size_t ha = arbase[band] + (size_t)(o_local * 8 + b) * kbv[band] + f_local;
    ((_Float16*)(wsb + AR_BYTE))[ha] = (_Float16)(xr * scale);
    ((_Float16*)(wsb + AI_BYTE))[ha] = (_Float16)(xi * scale);
}

// idft unit u in [0,480): ttile=u%24, mt=u/24 (mt<4 -> band4 first)
__device__ __forceinline__ void dev_idft(int u, int tid, const char* __restrict__ wsb,
                                         const float* __restrict__ bias,
                                         float* __restrict__ out,
                                         _Float16* AsR, _Float16* AsI,
                                         _Float16* BsC, _Float16* BsS) {
    const int n_ov[5] = {25,25,25,25,28};
    const int kbv[5]  = {128,128,128,128,512};
    const size_t arbase[5] = {0, 32768, 65536, 98304, 131072};   // halfs
    const size_t tbase[5]  = {0, 196608, 393216, 589824, 786432};// halfs
    int mt = u / 24;
    int col0 = (u % 24) * 64;
    int band, row0b;
    if (mt < 4) { band = 4;            row0b = mt * 64; }
    else        { band = (mt - 4) >> 2; row0b = ((mt - 4) & 3) * 64; }
    int Kb = kbv[band];
    int nkt = Kb / 64;                   // 2 or 8
    const char* Ar_b = wsb + AR_BYTE + arbase[band] * 2;
    const char* Ai_b = wsb + AI_BYTE + arbase[band] * 2;
    const char* Tc_b = wsb + TC_BYTE + tbase[band] * 2;
    const char* Ts_b = wsb + TS_BYTE + tbase[band] * 2;
    int wid = tid >> 6, lane = tid & 63;
    int wr = wid >> 1, wc = wid & 1;
    f32x4 accE[2][2] = {};
    f32x4 accO[2][2] = {};

    auto stage = [&](int kt, int buf) {      // 8 GL16 per thread
        int k0 = kt * 64;
        #pragma unroll
        for (int it = 0; it < 2; ++it) {
            int cb = it * 256 + wid * 64;
            int c = cb + lane;
            int ar = c >> 3, cir = c & 7;
            int cirs = cir ^ (ar & 7);       // swizzle in SOURCE addr
            size_t aoff = ((size_t)(row0b + ar) * Kb + k0) * 2 + cirs * 16;
            size_t boff = ((size_t)(col0 + ar) * Kb + k0) * 2 + cirs * 16;
            GL16(Ar_b + aoff, (char*)AsR + buf * 8192 + cb * 16);
            GL16(Ai_b + aoff, (char*)AsI + buf * 8192 + cb * 16);
            GL16(Tc_b + boff, (char*)BsC + buf * 8192 + cb * 16);
            GL16(Ts_b + boff, (char*)BsS + buf * 8192 + cb * 16);
        }
    };
    stage(0, 0);
    for (int kt = 0; kt < nkt; ++kt) {
        int cur = kt & 1;
        asm volatile("s_waitcnt vmcnt(0)" ::: "memory");
        __syncthreads();
        if (kt + 1 < nkt) stage(kt + 1, cur ^ 1);
        #pragma unroll
        for (int ks = 0; ks < 2; ++ks) {
            f16x8 avR[2], avI[2], bvC[2], bvS[2];
            #pragma unroll
            for (int m = 0; m < 2; ++m) {
                int r = wr * 32 + m * 16 + (lane & 15);
                int g = (ks * 4 + (lane >> 4)) ^ (r & 7);
                avR[m] = *(const f16x8*)(AsR + cur * 4096 + r * 64 + g * 8);
                avI[m] = *(const f16x8*)(AsI + cur * 4096 + r * 64 + g * 8);
            }
            #pragma unroll
            for (int n = 0; n < 2; ++n) {
                int r = wc * 32 + n * 16 + (lane & 15);
                int g = (ks * 4 + (lane >> 4)) ^ (r & 7);
                bvC[n] = *(const f16x8*)(BsC + cur * 4096 + r * 64 + g * 8);
                bvS[n] = *(const f16x8*)(BsS + cur * 4096 + r * 64 + g * 8);
            }
            #pragma unroll
            for (int m = 0; m < 2; ++m)
                #pragma unroll
                for (int n = 0; n < 2; ++n) {
                    accE[m][n] = __builtin_amdgcn_mfma_f32_16x16x32_f16(
                        avR[m], bvC[n], accE[m][n], 0, 0, 0);
                    accO[m][n] = __builtin_amdgcn_mfma_f32_16x16x32_f16(
                        avI[m], bvS[n], accO[m][n], 0, 0, 0);
                }
        }
    }

    int n_o8 = n_ov[band] * 8;
    #pragma unroll
    for (int m = 0; m < 2; ++m)
        #pragma unroll
        for (int n = 0; n < 2; ++n) {
            int t = col0 + wc * 32 + n * 16 + (lane & 15);
            int rowb = row0b + wr * 32 + m * 16 + (lane >> 4) * 4;
            #pragma unroll
            for (int j = 0; j < 4; ++j) {
                int prb = rowb + j;
                if (prb < n_o8) {
                    int o = band * 25 + (prb >> 3);
                    int b = prb & 7;
                    float E = accE[m][n][j], O = accO[m][n][j];
                    float bv = bias[o];
                    size_t rb = ((size_t)b * COUT + o) * TOUT;
                    if (t <= 1500)
                        out[rb + t] = E + O + bv;
                    if (t >= 25 && t <= 1499)
                        out[rb + 3000 - t] = E - O + bv;
                }
            }
        }
}

// ================= standalone kernels (r16 fallback path) ===============
__global__ __launch_bounds__(256) void k_prep(const float* __restrict__ sig,
                                              const float* __restrict__ w,
                                              char* __restrict__ wsb) {
    __shared__ float wL[CIN * KW];
    dev_prep(blockIdx.x, threadIdx.x, sig, w, wsb, wL);
}
__global__ __launch_bounds__(256) void k_dft_mm(const char* __restrict__ wsb,
                                                float* __restrict__ Sp) {
    __shared__ __align__(16) _Float16 AsB[2 * 8192];
    __shared__ __align__(16) _Float16 BsB[2 * 8192];
    dev_dft(blockIdx.x, threadIdx.x, wsb, Sp, AsB, BsB);
}
__global__ __launch_bounds__(256) void k_mix(const float* __restrict__ Sp,
                                             const _Float16* __restrict__ Wc,
                                             char* __restrict__ wsb) {
    __shared__ float s_re[8 * 72];
    __shared__ float s_im[8 * 72];
    dev_mix(blockIdx.x, threadIdx.x, Sp, Wc, wsb, s_re, s_im);
}
__global__ __launch_bounds__(256) void k_idft_mm(const char* __restrict__ wsb,
                                                 const float* __restrict__ bias,
                                                 float* __restrict__ out) {
    __shared__ __align__(16) _Float16 AsR[2 * 4096];
    __shared__ __align__(16) _Float16 AsI[2 * 4096];
    __shared__ __align__(16) _Float16 BsC[2 * 4096];
    __shared__ __align__(16) _Float16 BsS[2 * 4096];
    dev_idft(blockIdx.x, threadIdx.x, wsb, bias, out, AsR, AsI, BsC, BsS);
}

// ================= fused cooperative kernel =============================
__global__ __launch_bounds__(256, 2) void k_fused(const float* __restrict__ sig,
                                                  const float* __restrict__ w,
                                                  const float* __restrict__ bias,
                                                  char* __restrict__ wsb,
                                                  float* __restrict__ Sp,
                                                  float* __restrict__ out) {
    __shared__ __align__(16) char ldsRaw[65536];
    cg::grid_group grid = cg::this_grid();
    int tid = threadIdx.x;
    const _Float16* Wc = (const _Float16*)(wsb + WC_BYTE);

    // phase 1: prep (4776 units)
    for (int u = blockIdx.x; u < 4776; u += gridDim.x) {
        dev_prep(u, tid, sig, w, wsb, (float*)ldsRaw);
        __syncthreads();
    }
    grid.sync();

    // phase 2: fwd GEMM (256 units, 64 KB LDS)
    for (int u = blockIdx.x; u < 256; u += gridDim.x) {
        dev_dft(u, tid, wsb, Sp, (_Float16*)ldsRaw, (_Float16*)(ldsRaw + 32768));
        __syncthreads();
    }
    grid.sync();

    // phase 3: mix (977 units)
    for (int u = blockIdx.x; u < 977; u += gridDim.x) {
        dev_mix(u, tid, Sp, Wc, wsb, (float*)ldsRaw, (float*)(ldsRaw + 2304));
        __syncthreads();
    }
    grid.sync();

    // phase 4: idft GEMM (480 units, 64 KB LDS)
    for (int u = blockIdx.x; u < 480; u += gridDim.x) {
        dev_idft(u, tid, wsb, bias, out,
                 (_Float16*)ldsRaw, (_Float16*)(ldsRaw + 16384),
                 (_Float16*)(ldsRaw + 32768), (_Float16*)(ldsRaw + 49152));
        __syncthreads();
    }
}

extern "C" void kernel_launch(void* const* d_in, const int* in_sizes, int n_in,
                              void* d_out, int out_size, void* d_ws, size_t ws_size,
                              hipStream_t stream) {
    const float* sig  = (const float*)d_in[0];   // (8,64,3000) f32
    const float* w    = (const float*)d_in[1];   // (128,64,25) f32
    const float* bias = (const float*)d_in[2];   // (128,) f32
    float* out = (float*)d_out;
    char* wsb = (char*)d_ws;
    float* Sp = (float*)(wsb + SP_BYTE);

    // One cooperative dispatch (tests the ~13 us/graph-node floor).
    int maxPerCU = 0;
    hipError_t qe = hipOccupancyMaxActiveBlocksPerMultiprocessor(&maxPerCU, k_fused, 256, 0);
    int nblk = (qe == hipSuccess && maxPerCU >= 2) ? 512 : 256;
    void* args[] = { (void*)&sig, (void*)&w, (void*)&bias, (void*)&wsb, (void*)&Sp, (void*)&out };
    hipError_t le = hipLaunchCooperativeKernel((const void*)k_fused, dim3(nblk), dim3(256),
                                               args, 0, stream);
    if (le != hipSuccess) {
        // Deterministic fallback: exact r16 4-kernel pipeline.
        k_prep   <<<dim3(4776), 256, 0, stream>>>(sig, w, wsb);
        k_dft_mm <<<dim3(256),  256, 0, stream>>>(wsb, Sp);
        k_mix    <<<dim3(977),  256, 0, stream>>>(Sp, (const _Float16*)(wsb + WC_BYTE), wsb);
        k_idft_mm<<<dim3(480),  256, 0, stream>>>(wsb, bias, out);
    }
}

// Round 22
// 57.403 us; speedup vs baseline: 3.4165x; 3.4165x over previous
//
#include <hip/hip_runtime.h>

#define L_SIG 3000
#define KPAD2 1536          // folded fwd K: 1504 -> 24*64
#define NB 8
#define CIN 64
#define COUT 128
#define KW 25
#define TOUT 2976
#define FMAXB 973
#define NTT 1536            // folded t range padded (24*64)

// ws byte layout (~33 MB; NO aliasing):
#define AE_BYTE   0
#define AO_BYTE   1572864
#define BC_BYTE   3145728
#define BS_BYTE   6291456
#define TC_BYTE   9437184
#define TS_BYTE   12582912
#define WC_BYTE   15728640
#define SP_BYTE   22544384
#define AR_BYTE   31457280
#define AI_BYTE   31981568

typedef _Float16 f16x8 __attribute__((ext_vector_type(8)));
typedef float f32x4 __attribute__((ext_vector_type(4)));

typedef __attribute__((address_space(1))) const unsigned GU;
typedef __attribute__((address_space(3))) unsigned LU;
#define GL16(g, l) __builtin_amdgcn_global_load_lds((GU*)(g), (LU*)(l), 16, 0, 0)

#define TWO_PI_OVER_L 0.00209439510239319549f

__device__ __forceinline__ float2 h2f2(unsigned u) {
    union { unsigned u; _Float16 h[2]; } p; p.u = u;
    return make_float2((float)p.h[0], (float)p.h[1]);
}
__device__ __forceinline__ unsigned f2h2(float a, float b) {
    union { unsigned u; _Float16 h[2]; } p;
    p.h[0] = (_Float16)a; p.h[1] = (_Float16)b; return p.u;
}

// ================= prep: fold | B | gen_T | w_dft(4x-i) | zero ==========
// blocks: [0,512) fold  [512,2560) Bcos/Bsin  [2560,4096) gen_T
//         [4096,4520) w_dft  [4520,4776) zero Ar/Ai
__global__ __launch_bounds__(256) void k_prep(const float* __restrict__ sig,
                                              const float* __restrict__ w,
                                              char* __restrict__ wsb) {
    __shared__ float wL[CIN * KW];
    const int startv[5] = {0,122,244,366,488};
    const int binsv[5]  = {123,123,123,123,485};
    int blk = blockIdx.x, tid = threadIdx.x;

    if (blk < 512) {                         // ---- fold: xe / xo (swizzled)
        const float* x = sig + (size_t)blk * L_SIG;
        _Float16* AE = (_Float16*)(wsb + AE_BYTE);
        _Float16* AO = (_Float16*)(wsb + AO_BYTE);
        for (int g2 = tid; g2 < 384; g2 += 256) {
            int half = (g2 >= 192);
            int g = g2 - (half ? 192 : 0);
            union { _Float16 h[8]; uint4 u; } p;
            p.u = make_uint4(0, 0, 0, 0);
            if (g < 188) {
                int k0 = g * 8;
                float4 f0 = *(const float4*)(x + k0);
                float4 f1 = *(const float4*)(x + k0 + 4);
                float4 m0 = *(const float4*)(x + 2992 - k0);
                float4 m1 = *(const float4*)(x + 2996 - k0);
                float mir0 = k0 ? x[3000 - k0] : 0.f;
                float fwd[8]  = {f0.x,f0.y,f0.z,f0.w,f1.x,f1.y,f1.z,f1.w};
                float span[8] = {m0.x,m0.y,m0.z,m0.w,m1.x,m1.y,m1.z,m1.w};
                #pragma unroll
                for (int j = 0; j < 8; ++j) {
                    int k = k0 + j;
                    float mv = (j == 0) ? mir0 : span[8 - j];   // x[3000-k]
                    float xe, xo;
                    if (k == 0)         { xe = fwd[0];      xo = 0.f; }
                    else if (k < 1500)  { xe = fwd[j] + mv; xo = fwd[j] - mv; }
                    else if (k == 1500) { xe = fwd[j];      xo = 0.f; }
                    else                { xe = 0.f;         xo = 0.f; }
                    p.h[j] = (_Float16)(half ? xo : xe);
                }
            }
            int gsw = (g & ~7) | ((g & 7) ^ (blk & 7));
            ((uint4*)(half ? AO : AE))[(size_t)blk * 192 + gsw] = p.u;
        }

    } else if (blk < 2560) {                 // ---- Bcos / Bsin (swizzled)
        int q = blk - 512;
        int isin = (q >= 1024);
        int f = q & 1023;
        _Float16* Bm = (_Float16*)(wsb + (isin ? BS_BYTE : BC_BYTE));
        int g = tid;
        if (g >= 192) return;
        union { _Float16 h[8]; uint4 u; } p;
        p.u = make_uint4(0, 0, 0, 0);
        if (f < FMAXB) {
            int k0 = g * 8;
            int m0 = (int)(((long long)f * k0) % 3000);
            float s0, c0, sw, cw;
            __sincosf((float)m0 * TWO_PI_OVER_L, &s0, &c0);
            __sincosf((float)f * TWO_PI_OVER_L, &sw, &cw);
            float rr = c0, ri = -s0;         // (cos, -sin) at k0
            #pragma unroll
            for (int j = 0; j < 8; ++j) {
                p.h[j] = (_Float16)(isin ? ri : rr);
                float nr = rr * cw + ri * sw;
                float ni = ri * cw - rr * sw;
                rr = nr; ri = ni;
            }
        }
        int gsw = (g & ~7) | ((g & 7) ^ (f & 7));
        ((uint4*)Bm)[(size_t)f * 192 + gsw] = p.u;

    } else if (blk < 4096) {                 // ---- Tcos / Tsin (per-band, linear)
        const int tb4[5] = {0, 24576, 49152, 73728, 98304};
        int t = blk - 2560;                  // 0..1535
        int m = tid >> 7;                    // 0 = cos, 1 = sin
        int gi = tid & 127;
        int band, g;
        if (gi < 64) { band = gi >> 4; g = gi & 15; }
        else         { band = 4;       g = gi - 64; }
        int Kb8 = (band < 4) ? 16 : 64;      // granules per row
        int bins = binsv[band];
        int fl0 = g * 8;
        int f0 = startv[band] + fl0;
        union { _Float16 h[8]; uint4 u; } p;
        p.u = make_uint4(0, 0, 0, 0);
        int m0 = (f0 * t) % 3000;
        float s0, c0, sw, cw;
        __sincosf((float)m0 * TWO_PI_OVER_L, &s0, &c0);
        __sincosf((float)t * TWO_PI_OVER_L, &sw, &cw);
        float rr = c0, ri = -s0;             // (cos, -sin) at f0
        #pragma unroll
        for (int j = 0; j < 8; ++j) {
            if (fl0 + j < bins) p.h[j] = (_Float16)(m ? ri : rr);
            float nr = rr * cw + ri * sw;    // advance f by 1
            float ni = ri * cw - rr * sw;
            rr = nr; ri = ni;
        }
        uint4* Tm = (uint4*)(wsb + (m ? TS_BYTE : TC_BYTE));
        Tm[(size_t)tb4[band] + (size_t)t * Kb8 + g] = p.u;

    } else if (blk < 4520) {                 // ---- weight DFT, 4x-parallel over i
        _Float16* Wc = (_Float16*)(wsb + WC_BYTE);
        const int n_ov[5]   = {25,25,25,25,28};
        const size_t wbase[5] = {0, 393600, 787200, 1180800, 1574400};  // halfs
        int q = blk - 4096;
        int o, fchunk;
        if (q < 200) { o = q >> 1; fchunk = q & 1; }          // bands 0-3
        else { int q2 = q - 200; o = 100 + (q2 >> 3); fchunk = q2 & 7; }  // band 4
        int band = min(o / 25, 4);
        int o_local = o - band * 25;
        int bins = binsv[band];
        const float* wrow = w + (size_t)o * CIN * KW;
        for (int k = tid; k < CIN * KW; k += 256) wL[k] = wrow[k];
        __syncthreads();
        int fl = tid & 63, iq = tid >> 6;    // f-lane, i-quarter
        int f = fchunk * 64 + fl;
        if (f >= bins) return;
        int n_o = n_ov[band];
        int fg = startv[band] + f;
        float ws_, wc_;
        __sincosf((float)fg * TWO_PI_OVER_L, &ws_, &wc_);
        float wr = wc_, wi = ws_;            // conj roots: +sin
        unsigned* outp = (unsigned*)Wc + (wbase[band] >> 1) + ((size_t)f * n_o + o_local) * 64;
        #pragma unroll 4
        for (int i = iq * 16; i < iq * 16 + 16; ++i) {
            float ar = 0.f, ai = 0.f;
            float rr = 1.0f, ri = 0.0f;
            const float* wv = wL + i * KW;
            #pragma unroll
            for (int t = 0; t < KW; ++t) {
                float x = wv[t];
                ar = fmaf(x, rr, ar);
                ai = fmaf(x, ri, ai);
                float nr = fmaf(-ri, wi, rr * wr);
                float ni = fmaf( ri, wr, rr * wi);
                rr = nr; ri = ni;
            }
            outp[i] = f2h2(ar, ai);
        }

    } else {                                 // ---- zero Ar+Ai (contiguous 1 MB)
        uint4* Az = (uint4*)(wsb + AR_BYTE);
        int q = blk - 4520;
        Az[(size_t)q * 256 + tid] = make_uint4(0, 0, 0, 0);   // 65536 uint4
    }
}

// ==== folded fwd MFMA GEMM, BK=128, NO split-K (12 drains, 256 blocks) ==
// grid (16, 8, 2): x = f-tile, y = Mtile, z = {re,im}. Sp[2f+z][row].
__global__ __launch_bounds__(256) void k_dft_mm(const char* __restrict__ wsb,
                                                float* __restrict__ Sp) {
    __shared__ _Float16 As[2][64 * 128];     // 32 KB
    __shared__ _Float16 Bs[2][64 * 128];     // 32 KB
    int z = blockIdx.z;
    const _Float16* A = (const _Float16*)(wsb + (z ? AO_BYTE : AE_BYTE));
    const _Float16* B = (const _Float16*)(wsb + (z ? BS_BYTE : BC_BYTE));
    int row0 = blockIdx.y * 64;
    int col0 = blockIdx.x * 64;
    const int nkt = 12;
    int tid = threadIdx.x, wid = tid >> 6, lane = tid & 63;
    int wr = wid >> 1, wc = wid & 1;
    f32x4 acc[2][2] = {};

    auto stage = [&](int kt, int buf) {      // 8 GL16 per thread
        int k0g = kt * 16;                   // granule offset in row
        #pragma unroll
        for (int it = 0; it < 4; ++it) {
            int cb = it * 256 + wid * 64;    // wave-uniform chunk base (of 1024)
            int c = cb + lane;
            int ar = c >> 4, cir = c & 15;
            GL16((const char*)A + ((size_t)(row0 + ar) * 192 + k0g + cir) * 16,
                 (char*)As[buf] + cb * 16);
            GL16((const char*)B + ((size_t)(col0 + ar) * 192 + k0g + cir) * 16,
                 (char*)Bs[buf] + cb * 16);
        }
    };
    stage(0, 0);
    for (int kt = 0; kt < nkt; ++kt) {
        int cur = kt & 1;
        asm volatile("s_waitcnt vmcnt(0)" ::: "memory");
        __syncthreads();
        if (kt + 1 < nkt) stage(kt + 1, cur ^ 1);
        #pragma unroll
        for (int ks = 0; ks < 4; ++ks) {
            f16x8 av[2], bv[2];
            #pragma unroll
            for (int m = 0; m < 2; ++m) {
                int r = wr * 32 + m * 16 + (lane & 15);
                int gq = ks * 4 + (lane >> 4);
                int g = (gq & ~7) | ((gq & 7) ^ (r & 7));
                av[m] = *(const f16x8*)(As[cur] + r * 128 + g * 8);
            }
            #pragma unroll
            for (int n = 0; n < 2; ++n) {
                int r = wc * 32 + n * 16 + (lane & 15);
                int gq = ks * 4 + (lane >> 4);
                int g = (gq & ~7) | ((gq & 7) ^ (r & 7));
                bv[n] = *(const f16x8*)(Bs[cur] + r * 128 + g * 8);
            }
            #pragma unroll
            for (int m = 0; m < 2; ++m)
                #pragma unroll
                for (int n = 0; n < 2; ++n)
                    acc[m][n] = __builtin_amdgcn_mfma_f32_16x16x32_f16(
                        av[m], bv[n], acc[m][n], 0, 0, 0);
        }
    }
    #pragma unroll
    for (int m = 0; m < 2; ++m)
        #pragma unroll
        for (int n = 0; n < 2; ++n) {
            int colf = col0 + wc * 32 + n * 16 + (lane & 15);
            int scol = 2 * colf + z;
            int rowb = row0 + wr * 32 + m * 16 + (lane >> 4) * 4;
            *(float4*)(Sp + (size_t)scol * 512 + rowb) = *(float4*)&acc[m][n];
        }
}

// ================ mix: one block per (band, f_local) bin ================
__global__ __launch_bounds__(256) void k_mix(const float* __restrict__ Sp,
                                             const _Float16* __restrict__ Wc,
                                             char* __restrict__ wsb) {
    __shared__ float s_re[8 * 72];           // [b][i], pitch 72
    __shared__ float s_im[8 * 72];
    const int startv[5] = {0,122,244,366,488};
    const int n_ov[5]   = {25,25,25,25,28};
    const int kbv[5]    = {128,128,128,128,512};
    const size_t wbase[5] = {0, 393600, 787200, 1180800, 1574400};  // halfs
    const size_t arbase[5] = {0, 32768, 65536, 98304, 131072};      // halfs
    const int cumb[6] = {0, 123, 246, 369, 492, 977};
    int blk = blockIdx.x, tid = threadIdx.x;
    int band = 0;
    while (blk >= cumb[band + 1]) band++;
    int f_local = blk - cumb[band];
    int fg = startv[band] + f_local;

    const float* p0 = Sp + (size_t)(2 * fg) * 512;      // re col (im at +512)
    #pragma unroll
    for (int e = 0; e < 2; ++e) {
        int row = tid + e * 256;                         // b*64+i
        int b = row >> 6, i = row & 63;
        s_re[b * 72 + i] = p0[row];
        s_im[b * 72 + i] = p0[512 + row];
    }
    __syncthreads();

    int o_local = tid >> 3, b = tid & 7;
    int n_o = n_ov[band];
    if (o_local >= n_o) return;
    const uint4* wp4 = (const uint4*)((const unsigned*)Wc + (wbase[band] >> 1) +
                                      ((size_t)f_local * n_o + o_local) * 64);
    const float* lre = s_re + b * 72;
    const float* lim = s_im + b * 72;
    float xr = 0.f, xi = 0.f;
    #pragma unroll
    for (int ii = 0; ii < 16; ++ii) {
        float4 r4 = *(const float4*)(lre + ii * 4);
        float4 i4 = *(const float4*)(lim + ii * 4);
        uint4 wq = wp4[ii];
        float2 wv;
        wv = h2f2(wq.x);
        xr = fmaf(r4.x, wv.x, xr); xr = fmaf(-i4.x, wv.y, xr);
        xi = fmaf(r4.x, wv.y, xi); xi = fmaf( i4.x, wv.x, xi);
        wv = h2f2(wq.y);
        xr = fmaf(r4.y, wv.x, xr); xr = fmaf(-i4.y, wv.y, xr);
        xi = fmaf(r4.y, wv.y, xi); xi = fmaf( i4.y, wv.x, xi);
        wv = h2f2(wq.z);
        xr = fmaf(r4.z, wv.x, xr); xr = fmaf(-i4.z, wv.y, xr);
        xi = fmaf(r4.z, wv.y, xi); xi = fmaf( i4.z, wv.x, xi);
        wv = h2f2(wq.w);
        xr = fmaf(r4.w, wv.x, xr); xr = fmaf(-i4.w, wv.y, xr);
        xi = fmaf(r4.w, wv.y, xi); xi = fmaf( i4.w, wv.x, xi);
    }
    float scale = (fg == 0 ? 1.0f : 2.0f) / 3000.0f;
    size_t ha = arbase[band] + (size_t)(o_local * 8 + b) * kbv[band] + f_local;
    ((_Float16*)(wsb + AR_BYTE))[ha] = (_Float16)(xr * scale);
    ((_Float16*)(wsb + AI_BYTE))[ha] = (_Float16)(xi * scale);
}

// == folded idft GEMM, MERGED E/O, BK=64, band-4-first dispatch ==========
// grid (24, 20): x = t-tile; y<4 -> band4 (8-drain long pole first),
//                y>=4 -> band (y-4)>>2, Mtile (y-4)&3.
__global__ __launch_bounds__(256) void k_idft_mm(const char* __restrict__ wsb,
                                                 const float* __restrict__ bias,
                                                 float* __restrict__ out) {
    __shared__ _Float16 AsR[2][4096];        // 16 KB
    __shared__ _Float16 AsI[2][4096];        // 16 KB
    __shared__ _Float16 BsC[2][4096];        // 16 KB
    __shared__ _Float16 BsS[2][4096];        // 16 KB
    const int n_ov[5] = {25,25,25,25,28};
    const int kbv[5]  = {128,128,128,128,512};
    const size_t arbase[5] = {0, 32768, 65536, 98304, 131072};   // halfs
    const size_t tbase[5]  = {0, 196608, 393216, 589824, 786432};// halfs
    int mt = blockIdx.y;                 // 0..19
    int band, row0b;
    if (mt < 4) { band = 4;            row0b = mt * 64; }        // band4 first
    else        { band = (mt - 4) >> 2; row0b = ((mt - 4) & 3) * 64; }
    int col0 = blockIdx.x * 64;          // t in [0,1536)
    int Kb = kbv[band];
    int nkt = Kb / 64;                   // 2 or 8
    const char* Ar_b = wsb + AR_BYTE + arbase[band] * 2;
    const char* Ai_b = wsb + AI_BYTE + arbase[band] * 2;
    const char* Tc_b = wsb + TC_BYTE + tbase[band] * 2;
    const char* Ts_b = wsb + TS_BYTE + tbase[band] * 2;
    int tid = threadIdx.x, wid = tid >> 6, lane = tid & 63;
    int wr = wid >> 1, wc = wid & 1;
    f32x4 accE[2][2] = {};
    f32x4 accO[2][2] = {};

    auto stage = [&](int kt, int buf) {      // 8 GL16 per thread
        int k0 = kt * 64;
        #pragma unroll
        for (int it = 0; it < 2; ++it) {
            int cb = it * 256 + wid * 64;
            int c = cb + lane;
            int ar = c >> 3, cir = c & 7;
            int cirs = cir ^ (ar & 7);       // swizzle in SOURCE addr
            size_t aoff = ((size_t)(row0b + ar) * Kb + k0) * 2 + cirs * 16;
            size_t boff = ((size_t)(col0 + ar) * Kb + k0) * 2 + cirs * 16;
            GL16(Ar_b + aoff, (char*)AsR[buf] + cb * 16);
            GL16(Ai_b + aoff, (char*)AsI[buf] + cb * 16);
            GL16(Tc_b + boff, (char*)BsC[buf] + cb * 16);
            GL16(Ts_b + boff, (char*)BsS[buf] + cb * 16);
        }
    };
    stage(0, 0);
    for (int kt = 0; kt < nkt; ++kt) {
        int cur = kt & 1;
        asm volatile("s_waitcnt vmcnt(0)" ::: "memory");
        __syncthreads();
        if (kt + 1 < nkt) stage(kt + 1, cur ^ 1);
        #pragma unroll
        for (int ks = 0; ks < 2; ++ks) {
            f16x8 avR[2], avI[2], bvC[2], bvS[2];
            #pragma unroll
            for (int m = 0; m < 2; ++m) {
                int r = wr * 32 + m * 16 + (lane & 15);
                int g = (ks * 4 + (lane >> 4)) ^ (r & 7);
                avR[m] = *(const f16x8*)(AsR[cur] + r * 64 + g * 8);
                avI[m] = *(const f16x8*)(AsI[cur] + r * 64 + g * 8);
            }
            #pragma unroll
            for (int n = 0; n < 2; ++n) {
                int r = wc * 32 + n * 16 + (lane & 15);
                int g = (ks * 4 + (lane >> 4)) ^ (r & 7);
                bvC[n] = *(const f16x8*)(BsC[cur] + r * 64 + g * 8);
                bvS[n] = *(const f16x8*)(BsS[cur] + r * 64 + g * 8);
            }
            #pragma unroll
            for (int m = 0; m < 2; ++m)
                #pragma unroll
                for (int n = 0; n < 2; ++n) {
                    accE[m][n] = __builtin_amdgcn_mfma_f32_16x16x32_f16(
                        avR[m], bvC[n], accE[m][n], 0, 0, 0);
                    accO[m][n] = __builtin_amdgcn_mfma_f32_16x16x32_f16(
                        avI[m], bvS[n], accO[m][n], 0, 0, 0);
                }
        }
    }

    // epilogue: out[t] = E+O (t<=1500); out[3000-t] = E-O (25<=t<=1499)
    int n_o8 = n_ov[band] * 8;
    #pragma unroll
    for (int m = 0; m < 2; ++m)
        #pragma unroll
        for (int n = 0; n < 2; ++n) {
            int t = col0 + wc * 32 + n * 16 + (lane & 15);
            int rowb = row0b + wr * 32 + m * 16 + (lane >> 4) * 4;
            #pragma unroll
            for (int j = 0; j < 4; ++j) {
                int prb = rowb + j;
                if (prb < n_o8) {
                    int o = band * 25 + (prb >> 3);
                    int b = prb & 7;
                    float E = accE[m][n][j], O = accO[m][n][j];
                    float bv = bias[o];
                    size_t rb = ((size_t)b * COUT + o) * TOUT;
                    if (t <= 1500)
                        out[rb + t] = E + O + bv;
                    if (t >= 25 && t <= 1499)
                        out[rb + 3000 - t] = E - O + bv;
                }
            }
        }
}

extern "C" void kernel_launch(void* const* d_in, const int* in_sizes, int n_in,
                              void* d_out, int out_size, void* d_ws, size_t ws_size,
                              hipStream_t stream) {
    const float* sig  = (const float*)d_in[0];   // (8,64,3000) f32
    const float* w    = (const float*)d_in[1];   // (128,64,25) f32
    const float* bias = (const float*)d_in[2];   // (128,) f32
    float* out = (float*)d_out;
    char* wsb = (char*)d_ws;
    _Float16* Wc  = (_Float16*)(wsb + WC_BYTE);
    float*    Sp  = (float*)(wsb + SP_BYTE);

    k_prep   <<<dim3(4776),     256, 0, stream>>>(sig, w, wsb);
    k_dft_mm <<<dim3(16, 8, 2), 256, 0, stream>>>(wsb, Sp);
    k_mix    <<<dim3(977),      256, 0, stream>>>(Sp, Wc, wsb);
    k_idft_mm<<<dim3(24, 20),   256, 0, stream>>>(wsb, bias, out);
}